// Round 3
// baseline (5653.527 us; speedup 1.0000x reference)
//
#include <hip/hip_runtime.h>

#define TT   64
#define NB   8
#define NN   512
#define HID  128
#define G4   512
#define EE   8192
#define SBLK 16
#define NTHR 256
#define KC   32
#define HP   132                  // hbuf row pitch (floats)
#define CHUNKF (G4*KC)            // 16384 floats = 64KB per chunk buffer

__device__ __forceinline__ float sigf(float x){ return 1.0f/(1.0f+expf(-x)); }

__device__ __forceinline__ void gload16(const float* g, float* l){
  __builtin_amdgcn_global_load_lds(
      (const __attribute__((address_space(1))) void*)g,
      (__attribute__((address_space(3))) void*)l, 16, 0, 0);
}

// Fused 3-layer LSTM scan. 256 blocks x 256 thr (4 waves), 16 seqs/block.
// Thread (ug, sq) owns 8 gates (units 2ug,2ug+1 x {i,f,g,o}) x 4 seqs.
// Weights DMA-streamed L2->LDS in double-buffered 64KB chunks (KC=32),
// XOR-swizzled (slot = kg ^ (ug&7)) for conflict-free unpadded rows.
__global__ __launch_bounds__(NTHR,1) void lstm_scan(
    const float* __restrict__ x,    const float* __restrict__ wih0,
    const float* __restrict__ whh0, const float* __restrict__ bih0, const float* __restrict__ bhh0,
    const float* __restrict__ wih1, const float* __restrict__ whh1,
    const float* __restrict__ bih1, const float* __restrict__ bhh1,
    const float* __restrict__ wih2, const float* __restrict__ whh2,
    const float* __restrict__ bih2, const float* __restrict__ bhh2,
    float* __restrict__ feats)
{
  __shared__ __align__(16) float Wbuf[2*CHUNKF];     // 128 KB
  __shared__ __align__(16) float hbuf[3*SBLK*HP];    // 24.75 KB
  __shared__ float xbuf[SBLK];

  const int tid  = threadIdx.x;
  const int lane = tid & 63, wvi = tid >> 6;
  const int ug   = tid >> 2, sq = tid & 3;           // ug 0..63, sq 0..3
  const int swz  = ug & 7;
  const int s0   = blockIdx.x * SBLK;
  const int b    = s0 >> 9, n0 = s0 & (NN-1);

  for (int i = tid; i < 3*SBLK*HP; i += NTHR) hbuf[i] = 0.0f;

  // thread's 8 gate rows: row(j) = 128*(j>>1) + 2*ug + (j&1), j = ty*2+un
  int wrowf[8];
  float bjA[8], bjB[8], bjC[8], w0g[8];
  #pragma unroll
  for (int j=0;j<8;j++){
    int r = 128*(j>>1) + 2*ug + (j&1);
    wrowf[j] = r*KC;
    bjA[j] = bih0[r] + bhh0[r];
    bjB[j] = bih1[r] + bhh1[r];
    bjC[j] = bih2[r] + bhh2[r];
    w0g[j] = wih0[r];
  }

  // DMA constants: call i covers 64 16B-slots; n enumerates (row r, slot s)
  int gofs[16];
  #pragma unroll
  for (int i=0;i<16;i++){
    int n = (wvi*16 + i)*64 + lane;
    int r = n >> 3, s = n & 7;
    int g = s ^ ((r>>1)&7);                // source k-group for this slot
    gofs[i] = r*HID + g*4;
  }

  float acc[8][4];
  float cst0[2][4], cst1[2][4], cst2[2][4], hlast[2][4];
  #pragma unroll
  for (int un=0;un<2;un++)
    #pragma unroll
    for (int i=0;i<4;i++){ cst0[un][i]=0.f; cst1[un][i]=0.f; cst2[un][i]=0.f; hlast[un][i]=0.f; }

  // prologue: DMA chunk 0 (whh0, k0=0) -> buf 0
  #pragma unroll
  for (int i=0;i<16;i++) gload16(whh0 + gofs[i], &Wbuf[(wvi*16+i)*256]);

  #pragma unroll 1
  for (int t=0;t<TT;t++){
    if (tid < SBLK) xbuf[tid] = x[(b*TT + t)*NN + n0 + tid];
    // chunk schedule: c>>2 selects {whh0, wih1, whh1, wih2, whh2}; k0=(c&3)*KC
    #pragma unroll 1
    for (int c=0;c<20;c++){
      __syncthreads();                     // drains DMA(c); protects buf reuse
      int nx = c + 1; if (nx == 20) nx = 0;
      {
        const float* m;
        switch (nx>>2){ case 0: m=whh0; break; case 1: m=wih1; break;
                        case 2: m=whh1; break; case 3: m=wih2; break;
                        default: m=whh2; }
        const float* msrc = m + (nx&3)*KC;
        float* dst = &Wbuf[(nx&1)*CHUNKF];
        #pragma unroll
        for (int i=0;i<16;i++) gload16(msrc + gofs[i], dst + (wvi*16+i)*256);
      }
      if      (c==0 ){ for (int j=0;j<8;j++) for (int i=0;i<4;i++) acc[j][i]=bjA[j]; }
      else if (c==4 ){ for (int j=0;j<8;j++) for (int i=0;i<4;i++) acc[j][i]=bjB[j]; }
      else if (c==12){ for (int j=0;j<8;j++) for (int i=0;i<4;i++) acc[j][i]=bjC[j]; }

      const int hl = (c<8)?0:((c<16)?1:2);
      const float* wb = &Wbuf[(c&1)*CHUNKF];
      const float* hp = &hbuf[(hl*SBLK + 4*sq)*HP + (c&3)*KC];

      #pragma unroll
      for (int kg=0;kg<8;kg++){
        const int kgp = ((kg ^ swz) << 2);
        float4 w4[8], hv[4];
        #pragma unroll
        for (int j=0;j<8;j++) w4[j] = *(const float4*)(wb + wrowf[j] + kgp);
        #pragma unroll
        for (int i=0;i<4;i++) hv[i] = *(const float4*)(hp + i*HP + 4*kg);
        #pragma unroll
        for (int j=0;j<8;j++)
          #pragma unroll
          for (int i=0;i<4;i++)
            acc[j][i] += w4[j].x*hv[i].x + w4[j].y*hv[i].y
                       + w4[j].z*hv[i].z + w4[j].w*hv[i].w;
      }

      #define CELL(LYR, CST, XT, LAST)                                          \
        { __syncthreads();                                                      \
          _Pragma("unroll")                                                     \
          for (int un=0;un<2;un++)                                              \
          _Pragma("unroll")                                                     \
          for (int i=0;i<4;i++){                                                \
            float iv=acc[0+un][i], fv=acc[2+un][i];                             \
            float gv=acc[4+un][i], ov=acc[6+un][i];                             \
            if (XT){ float xv=xbuf[4*sq+i];                                     \
                     iv+=xv*w0g[0+un]; fv+=xv*w0g[2+un];                        \
                     gv+=xv*w0g[4+un]; ov+=xv*w0g[6+un]; }                      \
            float cn = sigf(fv)*CST[un][i] + sigf(iv)*tanhf(gv);                \
            CST[un][i]=cn; float hn = sigf(ov)*tanhf(cn);                       \
            hbuf[((LYR)*SBLK + 4*sq+i)*HP + 2*ug+un] = hn;                      \
            if (LAST){ hlast[un][i]=hn; } } }

      if      (c==3 ) CELL(0, cst0, 1, 0)
      else if (c==11) CELL(1, cst1, 0, 0)
      else if (c==19) CELL(2, cst2, 0, 1)
      #undef CELL
    }
  }
  #pragma unroll
  for (int un=0;un<2;un++)
    #pragma unroll
    for (int i=0;i<4;i++)
      feats[(s0 + 4*sq + i)*HID + 2*ug + un] = hlast[un][i];
}

// xl = in @ W^T ; optional input transform relu(in + pre_bias)
template<int KOUT>
__global__ void gcn_gemm(const float* __restrict__ in, const float* __restrict__ W,
                         const float* __restrict__ pre_bias, float* __restrict__ out)
{
  int id  = blockIdx.x*256 + threadIdx.x;
  int row = id / KOUT;
  int o   = id & (KOUT-1);
  const float4* a4 = (const float4*)(in + row*HID);
  const float4* w4 = (const float4*)(W + o*HID);
  float acc = 0.f;
  if (pre_bias){
    const float4* b4 = (const float4*)pre_bias;
    #pragma unroll 8
    for (int k=0;k<HID/4;k++){
      float4 av=a4[k], wv=w4[k], bv=b4[k];
      acc += fmaxf(av.x+bv.x,0.f)*wv.x + fmaxf(av.y+bv.y,0.f)*wv.y
           + fmaxf(av.z+bv.z,0.f)*wv.z + fmaxf(av.w+bv.w,0.f)*wv.w;
    }
  } else {
    #pragma unroll 8
    for (int k=0;k<HID/4;k++){
      float4 av=a4[k], wv=w4[k];
      acc += av.x*wv.x + av.y*wv.y + av.z*wv.z + av.w*wv.w;
    }
  }
  out[id] = acc;
}

__global__ void deg_init(float* deg){
  int i = blockIdx.x*256 + threadIdx.x;
  if (i < NN) deg[i] = 1.0f;             // self-loop
}
__global__ void deg_edges(const int* __restrict__ ei, float* deg){
  int e = blockIdx.x*256 + threadIdx.x;
  if (e < EE) atomicAdd(&deg[ei[EE+e]], 1.0f);
}
// dense normalized adjacency: A[dst][src] += dis[src]*dis[dst]; diag += 1/deg
__global__ void build_A(const int* __restrict__ ei, const float* __restrict__ deg,
                        float* __restrict__ A){
  int e = blockIdx.x*256 + threadIdx.x;
  if (e < EE){
    int s = ei[e], d = ei[EE+e];
    atomicAdd(&A[d*NN+s], rsqrtf(deg[s])*rsqrtf(deg[d]));
  } else if (e < EE+NN){
    int n = e - EE;
    atomicAdd(&A[n*NN+n], 1.0f/deg[n]);
  }
}

// Y[b,n,:] = sum_m A[n,m] * X[b,m,:]  (dense aggregation, 16 rows/block)
template<int KOUT>
__global__ __launch_bounds__(512) void gcn_agg(const float* __restrict__ A,
    const float* __restrict__ X, float* __restrict__ Y)
{
  const int F4 = KOUT/4;
  const int TN = 16;
  __shared__ __align__(16) float As[TN*NN];
  const int b = blockIdx.x, n0 = blockIdx.y*TN;
  const int tid = threadIdx.x;
  const int f4 = tid & (F4-1), nr = tid / F4;
  for (int i = tid; i < TN*NN; i += TN*F4) As[i] = A[n0*NN + i];
  __syncthreads();
  const float* Xb = X + b*NN*KOUT + f4*4;
  const float* Ar = As + nr*NN;
  float4 s = {0,0,0,0};
  #pragma unroll 4
  for (int m=0;m<NN;m++){
    float a = Ar[m];
    float4 xv = *(const float4*)(Xb + m*KOUT);
    s.x += a*xv.x; s.y += a*xv.y; s.z += a*xv.z; s.w += a*xv.w;
  }
  *(float4*)(Y + (b*NN + n0 + nr)*KOUT + f4*4) = s;
}

// out[b] = mean_n relu(agg2+b2) . cls_w + cls_b
__global__ void finalize(const float* __restrict__ agg2, const float* __restrict__ b2,
                         const float* __restrict__ clw, const float* __restrict__ clb,
                         float* __restrict__ out)
{
  __shared__ float red[256];
  int bb = blockIdx.x, tid = threadIdx.x;
  float acc = 0.f;
  for (int i = tid; i < NN*64; i += 256){
    int j = i & 63;
    float v = agg2[bb*NN*64 + i] + b2[j];
    acc += fmaxf(v, 0.f) * clw[j];
  }
  red[tid] = acc; __syncthreads();
  for (int sfd=128; sfd>0; sfd>>=1){
    if (tid < sfd) red[tid] += red[tid+sfd];
    __syncthreads();
  }
  if (tid==0) out[bb] = red[0]*(1.0f/NN) + clb[0];
}

extern "C" void kernel_launch(void* const* d_in, const int* in_sizes, int n_in,
                              void* d_out, int out_size, void* d_ws, size_t ws_size,
                              hipStream_t stream)
{
  const float* x    = (const float*)d_in[0];
  const int*   ei   = (const int*)  d_in[1];
  const float* wih0 = (const float*)d_in[2];
  const float* whh0 = (const float*)d_in[3];
  const float* bih0 = (const float*)d_in[4];
  const float* bhh0 = (const float*)d_in[5];
  const float* wih1 = (const float*)d_in[6];
  const float* whh1 = (const float*)d_in[7];
  const float* bih1 = (const float*)d_in[8];
  const float* bhh1 = (const float*)d_in[9];
  const float* wih2 = (const float*)d_in[10];
  const float* whh2 = (const float*)d_in[11];
  const float* bih2 = (const float*)d_in[12];
  const float* bhh2 = (const float*)d_in[13];
  const float* g1w  = (const float*)d_in[14];
  const float* g1b  = (const float*)d_in[15];
  const float* g2w  = (const float*)d_in[16];
  const float* g2b  = (const float*)d_in[17];
  const float* clw  = (const float*)d_in[18];
  const float* clb  = (const float*)d_in[19];
  float* out = (float*)d_out;

  char* ws = (char*)d_ws;
  float* feats = (float*)(ws);                 // [4096,128]  2 MB
  float* xl1   = (float*)(ws + 2097152);       // [8,512,128] 2 MB
  float* agg1  = (float*)(ws + 4194304);       // [8,512,128] 2 MB
  float* xl2   = (float*)(ws + 6291456);       // [8,512,64]  1 MB
  float* agg2  = (float*)(ws + 7340032);       // [8,512,64]  1 MB
  float* A     = (float*)(ws + 8388608);       // [512,512]   1 MB
  float* deg   = (float*)(ws + 9437184);       // [512]

  hipMemsetAsync(A, 0, NN*NN*sizeof(float), stream);
  deg_init <<<2, 256, 0, stream>>>(deg);
  deg_edges<<<EE/256, 256, 0, stream>>>(ei, deg);
  build_A  <<<(EE+NN+255)/256, 256, 0, stream>>>(ei, deg, A);

  lstm_scan<<<256, NTHR, 0, stream>>>(x, wih0, whh0, bih0, bhh0,
      wih1, whh1, bih1, bhh1, wih2, whh2, bih2, bhh2, feats);

  gcn_gemm<128><<<(4096*128)/256, 256, 0, stream>>>(feats, g1w, nullptr, xl1);
  gcn_agg<128><<<dim3(NB, NN/16), 512, 0, stream>>>(A, xl1, agg1);
  gcn_gemm<64><<<(4096*64)/256, 256, 0, stream>>>(agg1, g2w, g1b, xl2);
  gcn_agg<64><<<dim3(NB, NN/16), 256, 0, stream>>>(A, xl2, agg2);
  finalize<<<NB, 256, 0, stream>>>(agg2, g2b, clw, clb, out);
}